// Round 1
// 368.059 us; speedup vs baseline: 1.2225x; 1.2225x over previous
//
#include <hip/hip_runtime.h>
#include <hip/hip_bf16.h>
#include <hip/hip_fp16.h>

// Problem constants (match reference)
static constexpr int CH     = 128;   // IN_CH == HID
static constexpr int NCLS   = 32;
static constexpr int NGRAPH = 256;

// Bucketed CSR build: buckets are 512-node ranges (bucket = dst >> 9).
static constexpr int BSHIFT = 9;
static constexpr int BW     = 1 << BSHIFT;   // 512 nodes per bucket
static constexpr int MAXB   = 256;

typedef _Float16 half8 __attribute__((ext_vector_type(8)));
typedef _Float16 half4 __attribute__((ext_vector_type(4)));
typedef float    f32x4 __attribute__((ext_vector_type(4)));
typedef float    f32x2 __attribute__((ext_vector_type(2)));

// fp8 (OCP e4m3) gather buffer: xs rows quantized with a static scale so
// layer-2 values (~0.01 raw) stay in e4m3 normal range (subnormals start
// at 2^-6; x64 puts sigma at ~0.6..6.4, max << 448).
static constexpr float FP8_SCALE = 64.0f;
static constexpr float FP8_INV   = 1.0f / 64.0f;

__device__ __forceinline__ f32x2 dec8(unsigned short u) {
  // two e4m3 bytes (low word) -> two f32
  return __builtin_amdgcn_cvt_pk_f32_fp8((int)u, false);
}
__device__ __forceinline__ unsigned char enc8(float v) {
  return (unsigned char)(__builtin_amdgcn_cvt_pk_fp8_f32(v, v, 0, false) & 0xFF);
}

// ---------------------------------------------------------------------------
// 1) init: block 0 sets bucket cursors to b*CAP (over-allocated regions;
//    no histogram/scan needed). blocks 1..128: W1,W2 -> fp16 transpose.
// ---------------------------------------------------------------------------
__global__ __launch_bounds__(256) void k_init_wt(
    int* __restrict__ gcur, int CAP, int NBUCK,
    const float* __restrict__ W1, const float* __restrict__ W2,
    _Float16* __restrict__ WhT1, _Float16* __restrict__ WhT2) {
  int t = threadIdx.x;
  if (blockIdx.x == 0) {
    if (t < NBUCK) gcur[t] = t * CAP;
    return;
  }
  int i = (blockIdx.x - 1) * 256 + t;       // 0..32767
  const float* W = (i < CH * CH) ? W1 : W2;
  _Float16* T   = (i < CH * CH) ? WhT1 : WhT2;
  int j = i & (CH * CH - 1);
  int k = j >> 7, n = j & 127;
  T[n * CH + k] = (_Float16)W[j];
}

// ---------------------------------------------------------------------------
// 2) scatter packed edges into over-allocated bucket regions.
//    pack = (dstlo << 17) | src   (dstlo < 512 -> 9 bits; src < 2^17)
// ---------------------------------------------------------------------------
__global__ __launch_bounds__(1024) void k_scatter(
    const int* __restrict__ src, const int* __restrict__ dst,
    int* __restrict__ gcur, int* __restrict__ ebuf, int E) {
  __shared__ int bcnt[MAXB];
  __shared__ int bbase[MAXB];
  int t = threadIdx.x;
  if (t < MAXB) bcnt[t] = 0;
  __syncthreads();
  int base = blockIdx.x * 8192;
  int s_[8], d_[8], r_[8];
  #pragma unroll
  for (int j = 0; j < 8; ++j) {
    int i = base + j * 1024 + t;
    if (i < E) {
      s_[j] = src[i];
      d_[j] = dst[i];
      r_[j] = atomicAdd(&bcnt[d_[j] >> BSHIFT], 1);
    }
  }
  __syncthreads();
  if (t < MAXB && bcnt[t]) bbase[t] = atomicAdd(&gcur[t], bcnt[t]);
  __syncthreads();
  #pragma unroll
  for (int j = 0; j < 8; ++j) {
    int i = base + j * 1024 + t;
    if (i < E) {
      int b = d_[j] >> BSHIFT;
      int p = ((d_[j] & (BW - 1)) << 17) | s_[j];
      ebuf[bbase[b] + r_[j]] = p;
    }
  }
}

// ---------------------------------------------------------------------------
// 3) per-bucket CSR build (packed edges, gapped CAP regions).
//    Writes offs/oend (gapped layout), dinv, csr.
// ---------------------------------------------------------------------------
__global__ __launch_bounds__(1024) void k_build(
    const int* __restrict__ ebuf, const int* __restrict__ gcur,
    int* __restrict__ offs, int* __restrict__ oend,
    float* __restrict__ dinv, int* __restrict__ csr, int N, int CAP) {
  __shared__ int sdeg[BW];
  __shared__ int sscan[BW];
  int b = blockIdx.x;
  int t = threadIdx.x;
  int lo = b << BSHIFT;
  int e0 = b * CAP;
  int e1 = gcur[b];                  // b*CAP + bucket count after scatter

  if (t < BW) sdeg[t] = 0;
  __syncthreads();
  for (int e = e0 + t; e < e1; e += 1024)
    atomicAdd(&sdeg[ebuf[e] >> 17], 1);
  __syncthreads();
  if (t < BW) sscan[t] = sdeg[t];
  __syncthreads();
  for (int st = 1; st < BW; st <<= 1) {
    int v = (t < BW && t >= st) ? sscan[t - st] : 0;
    __syncthreads();
    if (t < BW) sscan[t] += v;
    __syncthreads();
  }
  if (t < BW) {
    int ex = b * CAP + sscan[t] - sdeg[t];   // gapped csr offset
    int n = lo + t;
    if (n < N) {
      offs[n] = ex;
      oend[n] = ex + sdeg[t];
      dinv[n] = 1.0f / sqrtf((float)(sdeg[t] + 1));
    }
    sscan[t] = ex;                            // fill cursor
  }
  __syncthreads();
  for (int e = e0 + t; e < e1; e += 1024) {
    int p = ebuf[e];
    int pos = atomicAdd(&sscan[p >> 17], 1);
    csr[pos] = p & 0x1FFFF;
  }
}

// ---------------------------------------------------------------------------
// MFMA GEMM: 64-row tiles, 4 waves x 16 rows, K=128 single shot, epilogue
// scales by dinv*64 -> fp8 e4m3 (scaled-xs form). The fp8 output halves the
// aggregation kernel's gather bytes AND its 64B line-request count.
// ---------------------------------------------------------------------------
__device__ __forceinline__ void stage_w(const _Float16* __restrict__ WhT,
                                        _Float16 (*Ws)[136], int tid) {
  #pragma unroll
  for (int l = 0; l < 8; ++l) {
    int idx = tid + l * 256;            // 0..2047 half8 chunks
    int n = idx >> 4, k8 = (idx & 15) << 3;
    *(half8*)&Ws[n][k8] = *(const half8*)(WhT + n * CH + k8);
  }
}

__device__ __forceinline__ void gemm_core64(
    const _Float16 (*As)[136], const _Float16 (*Ws)[136],
    const float* __restrict__ dinv, unsigned char* __restrict__ C,
    int row0, int M, int tid) {
  int lane = tid & 63, wave = tid >> 6;
  int quad = lane >> 4, sub = lane & 15;
  int m0 = wave * 16;

  f32x4 acc[8];
  #pragma unroll
  for (int j = 0; j < 8; ++j) acc[j] = (f32x4){0.f, 0.f, 0.f, 0.f};

  #pragma unroll
  for (int kc = 0; kc < 4; ++kc) {
    int ko = kc * 32 + quad * 8;
    half8 a = *(const half8*)&As[m0 + sub][ko];
    #pragma unroll
    for (int nt = 0; nt < 8; ++nt) {
      half8 b = *(const half8*)&Ws[nt * 16 + sub][ko];
      acc[nt] = __builtin_amdgcn_mfma_f32_16x16x32_f16(a, b, acc[nt], 0, 0, 0);
    }
  }
  #pragma unroll
  for (int r = 0; r < 4; ++r) {
    int row = row0 + m0 + quad * 4 + r;
    if (row < M) {
      float d = dinv[row] * FP8_SCALE;
      #pragma unroll
      for (int nt = 0; nt < 8; ++nt)
        C[(size_t)row * CH + nt * 16 + sub] = enc8(acc[nt][r] * d);
    }
  }
}

// A input fp32 (layer 1: x), packed half4 LDS stores
__global__ __launch_bounds__(256) void k_gemm_f32(
    const float* __restrict__ A, const _Float16* __restrict__ WhT,
    const float* __restrict__ dinv, unsigned char* __restrict__ C, int M) {
  __shared__ _Float16 As[64][136];
  __shared__ _Float16 Ws[128][136];
  int tid = threadIdx.x;
  int row0 = blockIdx.x * 64;
  #pragma unroll
  for (int l = 0; l < 8; ++l) {
    int idx = tid + l * 256;
    int r = idx >> 5, c4 = (idx & 31) << 2;
    int rr = row0 + r; if (rr >= M) rr = M - 1;
    float4 v = *(const float4*)(A + (size_t)rr * CH + c4);
    half4 hv = { (_Float16)v.x, (_Float16)v.y, (_Float16)v.z, (_Float16)v.w };
    *(half4*)&As[r][c4] = hv;
  }
  stage_w(WhT, Ws, tid);
  __syncthreads();
  gemm_core64(As, Ws, dinv, C, row0, M, tid);
}

// A input fp16 (layer 2: h)
__global__ __launch_bounds__(256) void k_gemm_f16(
    const _Float16* __restrict__ A, const _Float16* __restrict__ WhT,
    const float* __restrict__ dinv, unsigned char* __restrict__ C, int M) {
  __shared__ _Float16 As[64][136];
  __shared__ _Float16 Ws[128][136];
  int tid = threadIdx.x;
  int row0 = blockIdx.x * 64;
  #pragma unroll
  for (int l = 0; l < 4; ++l) {
    int idx = tid + l * 256;
    int r = idx >> 4, c8 = (idx & 15) << 3;
    int rr = row0 + r; if (rr >= M) rr = M - 1;
    *(half8*)&As[r][c8] = *(const half8*)(A + (size_t)rr * CH + c8);
  }
  stage_w(WhT, Ws, tid);
  __syncthreads();
  gemm_core64(As, Ws, dinv, C, row0, M, tid);
}

// ---------------------------------------------------------------------------
// Aggregation (pull, CSR): xs pre-scaled fp8 e4m3 (x64). Rows are 128B:
// 64 lanes x ushort (2 channels/lane). TWO nodes per wave in lockstep
// (8 gathers in flight); tails drain via MASKED 4-in-flight iterations
// (clamped edge position + fma mask) -- no serial 1-in-flight drain.
// ---------------------------------------------------------------------------
__global__ __launch_bounds__(256) void k_agg(
    const unsigned char* __restrict__ xs, const int* __restrict__ csr,
    const int* __restrict__ offs, const int* __restrict__ oend,
    const float* __restrict__ dinv, const float* __restrict__ bias,
    __half* __restrict__ out, int N) {
  int wid  = blockIdx.x * 4 + (threadIdx.x >> 6);
  int lane = threadIdx.x & 63;
  int nA = wid * 2, nB = nA + 1;
  if (nA >= N) return;
  bool hasB = (nB < N);
  const unsigned short* base = (const unsigned short*)xs;  // row = 64 ushorts

  int eA = offs[nA], endA = oend[nA];
  int eB = hasB ? offs[nB] : 0;
  int endB = hasB ? oend[nB] : 0;

  f32x2 sfA = dec8(base[(size_t)nA * 64 + lane]);
  float axA = sfA[0], ayA = sfA[1], bxA = 0.f, byA = 0.f;
  float axB = 0.f, ayB = 0.f, bxB = 0.f, byB = 0.f;
  if (hasB) {
    f32x2 sfB = dec8(base[(size_t)nB * 64 + lane]);
    axB = sfB[0]; ayB = sfB[1];
  }

  // lockstep: 4 edges of A + 4 edges of B per iteration (8 gathers in flight)
  while (eA + 4 <= endA && eB + 4 <= endB) {
    int a0 = csr[eA], a1 = csr[eA + 1], a2 = csr[eA + 2], a3 = csr[eA + 3];
    int b0 = csr[eB], b1 = csr[eB + 1], b2 = csr[eB + 2], b3 = csr[eB + 3];
    unsigned short uA0 = base[(size_t)a0 * 64 + lane];
    unsigned short uA1 = base[(size_t)a1 * 64 + lane];
    unsigned short uA2 = base[(size_t)a2 * 64 + lane];
    unsigned short uA3 = base[(size_t)a3 * 64 + lane];
    unsigned short uB0 = base[(size_t)b0 * 64 + lane];
    unsigned short uB1 = base[(size_t)b1 * 64 + lane];
    unsigned short uB2 = base[(size_t)b2 * 64 + lane];
    unsigned short uB3 = base[(size_t)b3 * 64 + lane];
    f32x2 vA0 = dec8(uA0), vA1 = dec8(uA1), vA2 = dec8(uA2), vA3 = dec8(uA3);
    f32x2 vB0 = dec8(uB0), vB1 = dec8(uB1), vB2 = dec8(uB2), vB3 = dec8(uB3);
    axA += vA0[0] + vA2[0]; ayA += vA0[1] + vA2[1];
    bxA += vA1[0] + vA3[0]; byA += vA1[1] + vA3[1];
    axB += vB0[0] + vB2[0]; ayB += vB0[1] + vB2[1];
    bxB += vB1[0] + vB3[0]; byB += vB1[1] + vB3[1];
    eA += 4; eB += 4;
  }

  // masked tail: 4 rows in flight, positions clamped to end-1, fma mask.
  // Clamped reads stay inside this node's own CSR region (valid entries).
  auto tail = [&](int e, int end, float& ax, float& ay, float& bx, float& by) {
    if (e >= end) return;
    int endm1 = end - 1;
    for (; e < end; e += 4) {
      int p1 = e + 1 < endm1 ? e + 1 : endm1;
      int p2 = e + 2 < endm1 ? e + 2 : endm1;
      int p3 = e + 3 < endm1 ? e + 3 : endm1;
      int s0 = csr[e], s1 = csr[p1], s2 = csr[p2], s3 = csr[p3];
      unsigned short u0 = base[(size_t)s0 * 64 + lane];
      unsigned short u1 = base[(size_t)s1 * 64 + lane];
      unsigned short u2 = base[(size_t)s2 * 64 + lane];
      unsigned short u3 = base[(size_t)s3 * 64 + lane];
      f32x2 v0 = dec8(u0), v1 = dec8(u1), v2 = dec8(u2), v3 = dec8(u3);
      float m1 = (e + 1 < end) ? 1.f : 0.f;
      float m2 = (e + 2 < end) ? 1.f : 0.f;
      float m3 = (e + 3 < end) ? 1.f : 0.f;
      ax += v0[0];                 ay += v0[1];
      bx  = fmaf(v1[0], m1, bx);   by  = fmaf(v1[1], m1, by);
      ax  = fmaf(v2[0], m2, ax);   ay  = fmaf(v2[1], m2, ay);
      bx  = fmaf(v3[0], m3, bx);   by  = fmaf(v3[1], m3, by);
    }
  };
  tail(eA, endA, axA, ayA, bxA, byA);
  if (hasB) tail(eB, endB, axB, ayB, bxB, byB);

  float bx0 = bias[2 * lane], bx1 = bias[2 * lane + 1];
  {
    float dn = dinv[nA] * FP8_INV;
    float rx = fmaf(axA + bxA, dn, bx0);
    float ry = fmaf(ayA + byA, dn, bx1);
    ((__half2*)out)[(size_t)nA * 64 + lane] =
        __floats2half2_rn(fmaxf(rx, 0.f), fmaxf(ry, 0.f));
  }
  if (hasB) {
    float dn = dinv[nB] * FP8_INV;
    float rx = fmaf(axB + bxB, dn, bx0);
    float ry = fmaf(ayB + byB, dn, bx1);
    ((__half2*)out)[(size_t)nB * 64 + lane] =
        __floats2half2_rn(fmaxf(rx, 0.f), fmaxf(ry, 0.f));
  }
}

// ---------------------------------------------------------------------------
// Pool + graph boundaries (batch sorted)
// ---------------------------------------------------------------------------
__global__ __launch_bounds__(128) void k_pool(
    const __half* __restrict__ h, const int* __restrict__ batch,
    float* __restrict__ gsum, int* __restrict__ gstart,
    int* __restrict__ gend, int N) {
  int ch = threadIdx.x;
  int n0 = blockIdx.x * 128;
  int n1 = n0 + 128; if (n1 > N) n1 = N;
  if (n0 >= N) return;
  for (int n = n0 + ch; n < n1; n += 128) {
    int g = batch[n];
    if (n == 0 || batch[n - 1] != g) gstart[g] = n;
    if (n == N - 1 || batch[n + 1] != g) gend[g] = n + 1;
  }
  float acc = 0.f;
  int curg = batch[n0];
  for (int n = n0; n < n1; ++n) {
    int g = batch[n];
    if (g != curg) {
      atomicAdd(&gsum[curg * CH + ch], acc);
      acc = 0.f; curg = g;
    }
    acc += __half2float(h[(size_t)n * CH + ch]);
  }
  atomicAdd(&gsum[curg * CH + ch], acc);
}

// ---------------------------------------------------------------------------
// FC
// ---------------------------------------------------------------------------
__global__ __launch_bounds__(64) void k_fc(
    const float* __restrict__ gsum, const int* __restrict__ gstart,
    const int* __restrict__ gend, const float* __restrict__ Wfc,
    const float* __restrict__ bfc, float* __restrict__ outp) {
  int g = blockIdx.x;
  int j = threadIdx.x;
  if (j >= NCLS) return;
  int cnt = gend[g] - gstart[g];
  float invc = 1.0f / fmaxf((float)cnt, 1.0f);
  float acc = 0.0f;
  for (int c = 0; c < CH; ++c)
    acc = fmaf(gsum[g * CH + c], Wfc[c * NCLS + j], acc);
  outp[g * NCLS + j] = fmaf(acc, invc, bfc[j]);
}

// ---------------------------------------------------------------------------
extern "C" void kernel_launch(void* const* d_in, const int* in_sizes, int n_in,
                              void* d_out, int out_size, void* d_ws, size_t ws_size,
                              hipStream_t stream) {
  const float* x    = (const float*)d_in[0];
  const int*   ei   = (const int*)d_in[1];
  const int*   batch= (const int*)d_in[2];
  const float* W1   = (const float*)d_in[3];
  const float* b1   = (const float*)d_in[4];
  const float* W2   = (const float*)d_in[5];
  const float* b2   = (const float*)d_in[6];
  const float* Wfc  = (const float*)d_in[7];
  const float* bfc  = (const float*)d_in[8];
  float* outp = (float*)d_out;

  const int N = in_sizes[0] / CH;       // 100000
  const int E = in_sizes[1] / 2;        // 3200000
  const int* src = ei;
  const int* dst = ei + E;
  const int NBUCK = (N + BW - 1) >> BSHIFT;   // 196
  // Over-allocated bucket capacity: mean + ~18 sigma (Binomial), fill-safe.
  const int CAP = (E / NBUCK) + (E / NBUCK) / 8 + 256;

  // Workspace carve (256B aligned). First three buffers zeroed by ONE memset.
  char* w = (char*)d_ws;
  size_t o = 0;
  auto carve = [&](size_t bytes) -> void* {
    o = (o + 255) & ~(size_t)255;
    void* p = w + o;
    o += bytes;
    return p;
  };
  float*    gsum   = (float*)   carve((size_t)NGRAPH * CH * 4);  // zeroed
  int*      gstart = (int*)     carve((size_t)NGRAPH * 4);       // zeroed
  int*      gend   = (int*)     carve((size_t)NGRAPH * 4);       // zeroed
  size_t zbytes = o;
  int*      offs   = (int*)     carve((size_t)N * 4);
  int*      oendb  = (int*)     carve((size_t)N * 4);
  int*      gcur   = (int*)     carve(MAXB * 4);
  int*      csr    = (int*)     carve((size_t)NBUCK * CAP * 4);
  float*    dinv   = (float*)   carve((size_t)N * 4);
  _Float16* WhT1   = (_Float16*)carve((size_t)CH * CH * 2);
  _Float16* WhT2   = (_Float16*)carve((size_t)CH * CH * 2);
  unsigned char* xsbuf = (unsigned char*)carve((size_t)N * CH);  // fp8 gather buffer
  __half*   hbuf   = (__half*)  carve((size_t)N * CH * 2);       // fp16 h
  (void)ws_size;

  // ebuf (packed edges, gapped) aliases hbuf: NBUCK*CAP*4 ~ 14.6MB <= 25.6MB
  int* ebuf = (int*)hbuf;

  (void)hipMemsetAsync(gsum, 0, zbytes, stream);

  const int GB64 = (N + 63) / 64;       // 1563
  const int GB   = (N + 127) / 128;
  const int AB   = (N + 7) / 8;         // 2 nodes/wave, 4 waves/block

  k_init_wt<<<129, 256, 0, stream>>>(gcur, CAP, NBUCK, W1, W2, WhT1, WhT2);
  k_scatter<<<(E + 8191) / 8192, 1024, 0, stream>>>(src, dst, gcur, ebuf, E);
  k_build  <<<NBUCK, 1024, 0, stream>>>(ebuf, gcur, offs, oendb, dinv, csr, N, CAP);

  // Layer 1: xs = fp8((x@W1)*dinv*64) ; h = fp16(relu(agg(xs)*dinv/64 + b1))
  k_gemm_f32<<<GB64, 256, 0, stream>>>(x, WhT1, dinv, xsbuf, N);
  k_agg<<<AB, 256, 0, stream>>>(xsbuf, csr, offs, oendb, dinv, b1, hbuf, N);
  // Layer 2
  k_gemm_f16<<<GB64, 256, 0, stream>>>((const _Float16*)hbuf, WhT2, dinv, xsbuf, N);
  k_agg<<<AB, 256, 0, stream>>>(xsbuf, csr, offs, oendb, dinv, b2, hbuf, N);

  // Pool (+ boundaries) + FC
  k_pool<<<GB, 128, 0, stream>>>(hbuf, batch, gsum, gstart, gend, N);
  k_fc<<<NGRAPH, 64, 0, stream>>>(gsum, gstart, gend, Wfc, bfc, outp);
  (void)out_size; (void)n_in;
}

// Round 2
// 360.507 us; speedup vs baseline: 1.2481x; 1.0209x over previous
//
#include <hip/hip_runtime.h>
#include <hip/hip_bf16.h>
#include <hip/hip_fp16.h>

// Problem constants (match reference)
static constexpr int CH     = 128;   // IN_CH == HID
static constexpr int NCLS   = 32;
static constexpr int NGRAPH = 256;

// Bucketed CSR build: buckets are 256-node ranges (bucket = dst >> 8).
// BSHIFT=8 -> 391 buckets: better CU utilization in k_build than 196.
static constexpr int BSHIFT = 8;
static constexpr int BW     = 1 << BSHIFT;   // 256 nodes per bucket
static constexpr int MAXB   = 512;

typedef _Float16 half8 __attribute__((ext_vector_type(8)));
typedef _Float16 half4 __attribute__((ext_vector_type(4)));
typedef float    f32x4 __attribute__((ext_vector_type(4)));
typedef float    f32x2 __attribute__((ext_vector_type(2)));

// fp8 (OCP e4m3) gather buffer: xs rows quantized with a static scale so
// layer-2 values (~0.01 raw) stay in e4m3 normal range.
static constexpr float FP8_SCALE = 64.0f;
static constexpr float FP8_INV   = 1.0f / 64.0f;

__device__ __forceinline__ f32x2 dec8(unsigned short u) {
  // two e4m3 bytes (low word) -> two f32 (one VALU op)
  return __builtin_amdgcn_cvt_pk_f32_fp8((int)u, false);
}
__device__ __forceinline__ unsigned char enc8(float v) {
  return (unsigned char)(__builtin_amdgcn_cvt_pk_fp8_f32(v, v, 0, false) & 0xFF);
}

// ---------------------------------------------------------------------------
// 1) init: block 0 sets bucket cursors to b*CAP and zeroes the fp8 pad row
//    (row N of xs; CSR padding points here so padded gathers add +0.0).
//    blocks 1..128: W1,W2 -> fp16 transpose.
// ---------------------------------------------------------------------------
__global__ __launch_bounds__(256) void k_init_wt(
    int* __restrict__ gcur, int CAP, int NBUCK, int* __restrict__ xzero,
    const float* __restrict__ W1, const float* __restrict__ W2,
    _Float16* __restrict__ WhT1, _Float16* __restrict__ WhT2) {
  int t = threadIdx.x;
  if (blockIdx.x == 0) {
    for (int i = t; i < NBUCK; i += 256) gcur[i] = i * CAP;
    if (t < 32) xzero[t] = 0;              // 128B zero row
    return;
  }
  int i = (blockIdx.x - 1) * 256 + t;       // 0..32767
  const float* W = (i < CH * CH) ? W1 : W2;
  _Float16* T   = (i < CH * CH) ? WhT1 : WhT2;
  int j = i & (CH * CH - 1);
  int k = j >> 7, n = j & 127;
  T[n * CH + k] = (_Float16)W[j];
}

// ---------------------------------------------------------------------------
// 2) scatter packed edges into over-allocated bucket regions.
//    pack = (dstlo << 17) | src   (dstlo < 256 -> 8 bits; src < 2^17)
// ---------------------------------------------------------------------------
__global__ __launch_bounds__(1024) void k_scatter(
    const int* __restrict__ src, const int* __restrict__ dst,
    int* __restrict__ gcur, int* __restrict__ ebuf, int E) {
  __shared__ int bcnt[MAXB];
  __shared__ int bbase[MAXB];
  int t = threadIdx.x;
  if (t < MAXB) bcnt[t] = 0;
  __syncthreads();
  int base = blockIdx.x * 8192;
  int s_[8], d_[8], r_[8];
  #pragma unroll
  for (int j = 0; j < 8; ++j) {
    int i = base + j * 1024 + t;
    if (i < E) {
      s_[j] = src[i];
      d_[j] = dst[i];
      r_[j] = atomicAdd(&bcnt[d_[j] >> BSHIFT], 1);
    }
  }
  __syncthreads();
  if (t < MAXB && bcnt[t]) bbase[t] = atomicAdd(&gcur[t], bcnt[t]);
  __syncthreads();
  #pragma unroll
  for (int j = 0; j < 8; ++j) {
    int i = base + j * 1024 + t;
    if (i < E) {
      int b = d_[j] >> BSHIFT;
      int p = ((d_[j] & (BW - 1)) << 17) | s_[j];
      ebuf[bbase[b] + r_[j]] = p;
    }
  }
}

// ---------------------------------------------------------------------------
// 3) per-bucket CSR build (packed edges, gapped CAP regions).
//    Per-node regions are 4-entry aligned; slots [deg, pdeg) are filled with
//    NPAD (= N, the zero row) so k_agg can read blind int4 chunks.
// ---------------------------------------------------------------------------
__global__ __launch_bounds__(1024) void k_build(
    const int* __restrict__ ebuf, const int* __restrict__ gcur,
    int* __restrict__ offs, int* __restrict__ oend,
    float* __restrict__ dinv, int* __restrict__ csr, int N, int CAP) {
  __shared__ int sdeg[BW];
  __shared__ int sscan[BW];
  int b = blockIdx.x;
  int t = threadIdx.x;
  int lo = b << BSHIFT;
  int e0 = b * CAP;
  int e1 = gcur[b];                  // b*CAP + bucket count after scatter

  if (t < BW) sdeg[t] = 0;
  __syncthreads();
  for (int e = e0 + t; e < e1; e += 1024)
    atomicAdd(&sdeg[ebuf[e] >> 17], 1);
  __syncthreads();
  if (t < BW) sscan[t] = (sdeg[t] + 3) & ~3;     // padded degree
  __syncthreads();
  for (int st = 1; st < BW; st <<= 1) {
    int v = (t < BW && t >= st) ? sscan[t - st] : 0;
    __syncthreads();
    if (t < BW) sscan[t] += v;
    __syncthreads();
  }
  if (t < BW) {
    int deg  = sdeg[t];
    int pdeg = (deg + 3) & ~3;
    int ex = b * CAP + sscan[t] - pdeg;          // 4-aligned (CAP%4==0)
    int n = lo + t;
    if (n < N) {
      offs[n] = ex;
      oend[n] = ex + deg;
      dinv[n] = 1.0f / sqrtf((float)(deg + 1));
      for (int q = deg; q < pdeg; ++q) csr[ex + q] = N;   // zero-row pad
    }
    sscan[t] = ex;                                // fill cursor
  }
  __syncthreads();
  for (int e = e0 + t; e < e1; e += 1024) {
    int p = ebuf[e];
    int pos = atomicAdd(&sscan[p >> 17], 1);
    csr[pos] = p & 0x1FFFF;
  }
}

// ---------------------------------------------------------------------------
// MFMA GEMM: 64-row tiles, 4 waves x 16 rows, K=128 single shot, epilogue
// scales by dinv*64 -> fp8 e4m3 (scaled-xs form).
// ---------------------------------------------------------------------------
__device__ __forceinline__ void stage_w(const _Float16* __restrict__ WhT,
                                        _Float16 (*Ws)[136], int tid) {
  #pragma unroll
  for (int l = 0; l < 8; ++l) {
    int idx = tid + l * 256;            // 0..2047 half8 chunks
    int n = idx >> 4, k8 = (idx & 15) << 3;
    *(half8*)&Ws[n][k8] = *(const half8*)(WhT + n * CH + k8);
  }
}

__device__ __forceinline__ void gemm_core64(
    const _Float16 (*As)[136], const _Float16 (*Ws)[136],
    const float* __restrict__ dinv, unsigned char* __restrict__ C,
    int row0, int M, int tid) {
  int lane = tid & 63, wave = tid >> 6;
  int quad = lane >> 4, sub = lane & 15;
  int m0 = wave * 16;

  f32x4 acc[8];
  #pragma unroll
  for (int j = 0; j < 8; ++j) acc[j] = (f32x4){0.f, 0.f, 0.f, 0.f};

  #pragma unroll
  for (int kc = 0; kc < 4; ++kc) {
    int ko = kc * 32 + quad * 8;
    half8 a = *(const half8*)&As[m0 + sub][ko];
    #pragma unroll
    for (int nt = 0; nt < 8; ++nt) {
      half8 b = *(const half8*)&Ws[nt * 16 + sub][ko];
      acc[nt] = __builtin_amdgcn_mfma_f32_16x16x32_f16(a, b, acc[nt], 0, 0, 0);
    }
  }
  #pragma unroll
  for (int r = 0; r < 4; ++r) {
    int row = row0 + m0 + quad * 4 + r;
    if (row < M) {
      float d = dinv[row] * FP8_SCALE;
      #pragma unroll
      for (int nt = 0; nt < 8; ++nt)
        C[(size_t)row * CH + nt * 16 + sub] = enc8(acc[nt][r] * d);
    }
  }
}

// A input fp32 (layer 1: x), packed half4 LDS stores
__global__ __launch_bounds__(256) void k_gemm_f32(
    const float* __restrict__ A, const _Float16* __restrict__ WhT,
    const float* __restrict__ dinv, unsigned char* __restrict__ C, int M) {
  __shared__ _Float16 As[64][136];
  __shared__ _Float16 Ws[128][136];
  int tid = threadIdx.x;
  int row0 = blockIdx.x * 64;
  #pragma unroll
  for (int l = 0; l < 8; ++l) {
    int idx = tid + l * 256;
    int r = idx >> 5, c4 = (idx & 31) << 2;
    int rr = row0 + r; if (rr >= M) rr = M - 1;
    float4 v = *(const float4*)(A + (size_t)rr * CH + c4);
    half4 hv = { (_Float16)v.x, (_Float16)v.y, (_Float16)v.z, (_Float16)v.w };
    *(half4*)&As[r][c4] = hv;
  }
  stage_w(WhT, Ws, tid);
  __syncthreads();
  gemm_core64(As, Ws, dinv, C, row0, M, tid);
}

// A input fp16 (layer 2: h)
__global__ __launch_bounds__(256) void k_gemm_f16(
    const _Float16* __restrict__ A, const _Float16* __restrict__ WhT,
    const float* __restrict__ dinv, unsigned char* __restrict__ C, int M) {
  __shared__ _Float16 As[64][136];
  __shared__ _Float16 Ws[128][136];
  int tid = threadIdx.x;
  int row0 = blockIdx.x * 64;
  #pragma unroll
  for (int l = 0; l < 4; ++l) {
    int idx = tid + l * 256;
    int r = idx >> 4, c8 = (idx & 15) << 3;
    int rr = row0 + r; if (rr >= M) rr = M - 1;
    *(half8*)&As[r][c8] = *(const half8*)(A + (size_t)rr * CH + c8);
  }
  stage_w(WhT, Ws, tid);
  __syncthreads();
  gemm_core64(As, Ws, dinv, C, row0, M, tid);
}

// ---------------------------------------------------------------------------
// Aggregation (pull, CSR): xs pre-scaled fp8 e4m3 (x64), rows 128B.
// VALU-diet version: 32-bit gather offsets ((s<<7)|lane2, one v_lshl_or_b32),
// f32x2 packed accumulators (v_pk_add_f32), int4 CSR chunk loads (regions are
// 4-aligned, padded with the zero row N) -> no masks, no clamps, no serial
// tail. Two nodes per wave in lockstep: 8 gathers + 2 dwordx4 in flight.
// ---------------------------------------------------------------------------
__global__ __launch_bounds__(256) void k_agg(
    const unsigned char* __restrict__ xs, const int* __restrict__ csr,
    const int* __restrict__ offs, const int* __restrict__ oend,
    const float* __restrict__ dinv, const float* __restrict__ bias,
    __half* __restrict__ out, int N) {
  int wid  = blockIdx.x * 4 + (threadIdx.x >> 6);
  int lane = threadIdx.x & 63;
  int nA = wid * 2, nB = nA + 1;
  if (nA >= N) return;
  bool hasB = (nB < N);
  unsigned int lane2 = (unsigned int)lane << 1;

  int eA = offs[nA];
  int cA = (oend[nA] - eA + 3) >> 2;                 // chunk count
  int eB = hasB ? offs[nB] : 0;
  int cB = hasB ? ((oend[nB] - eB + 3) >> 2) : 0;

  f32x2 aA0 = dec8(*(const unsigned short*)(xs + (((unsigned int)nA << 7) | lane2)));
  f32x2 aA1 = {0.f, 0.f};
  f32x2 aB0 = {0.f, 0.f}, aB1 = {0.f, 0.f};
  if (hasB)
    aB0 = dec8(*(const unsigned short*)(xs + (((unsigned int)nB << 7) | lane2)));

  while (cA > 0 && cB > 0) {
    int4 ca = *(const int4*)(csr + eA);
    int4 cb = *(const int4*)(csr + eB);
    unsigned short uA0 = *(const unsigned short*)(xs + (((unsigned int)ca.x << 7) | lane2));
    unsigned short uA1 = *(const unsigned short*)(xs + (((unsigned int)ca.y << 7) | lane2));
    unsigned short uA2 = *(const unsigned short*)(xs + (((unsigned int)ca.z << 7) | lane2));
    unsigned short uA3 = *(const unsigned short*)(xs + (((unsigned int)ca.w << 7) | lane2));
    unsigned short uB0 = *(const unsigned short*)(xs + (((unsigned int)cb.x << 7) | lane2));
    unsigned short uB1 = *(const unsigned short*)(xs + (((unsigned int)cb.y << 7) | lane2));
    unsigned short uB2 = *(const unsigned short*)(xs + (((unsigned int)cb.z << 7) | lane2));
    unsigned short uB3 = *(const unsigned short*)(xs + (((unsigned int)cb.w << 7) | lane2));
    aA0 += dec8(uA0); aA1 += dec8(uA1); aA0 += dec8(uA2); aA1 += dec8(uA3);
    aB0 += dec8(uB0); aB1 += dec8(uB1); aB0 += dec8(uB2); aB1 += dec8(uB3);
    eA += 4; eB += 4; --cA; --cB;
  }
  while (cA > 0) {
    int4 ca = *(const int4*)(csr + eA);
    unsigned short u0 = *(const unsigned short*)(xs + (((unsigned int)ca.x << 7) | lane2));
    unsigned short u1 = *(const unsigned short*)(xs + (((unsigned int)ca.y << 7) | lane2));
    unsigned short u2 = *(const unsigned short*)(xs + (((unsigned int)ca.z << 7) | lane2));
    unsigned short u3 = *(const unsigned short*)(xs + (((unsigned int)ca.w << 7) | lane2));
    aA0 += dec8(u0); aA1 += dec8(u1); aA0 += dec8(u2); aA1 += dec8(u3);
    eA += 4; --cA;
  }
  while (cB > 0) {
    int4 cb = *(const int4*)(csr + eB);
    unsigned short u0 = *(const unsigned short*)(xs + (((unsigned int)cb.x << 7) | lane2));
    unsigned short u1 = *(const unsigned short*)(xs + (((unsigned int)cb.y << 7) | lane2));
    unsigned short u2 = *(const unsigned short*)(xs + (((unsigned int)cb.z << 7) | lane2));
    unsigned short u3 = *(const unsigned short*)(xs + (((unsigned int)cb.w << 7) | lane2));
    aB0 += dec8(u0); aB1 += dec8(u1); aB0 += dec8(u2); aB1 += dec8(u3);
    eB += 4; --cB;
  }

  float2 bxy = *(const float2*)(bias + 2 * lane);
  {
    f32x2 s = aA0 + aA1;
    float dn = dinv[nA] * FP8_INV;
    float rx = fmaf(s[0], dn, bxy.x);
    float ry = fmaf(s[1], dn, bxy.y);
    ((__half2*)out)[(size_t)nA * 64 + lane] =
        __floats2half2_rn(fmaxf(rx, 0.f), fmaxf(ry, 0.f));
  }
  if (hasB) {
    f32x2 s = aB0 + aB1;
    float dn = dinv[nB] * FP8_INV;
    float rx = fmaf(s[0], dn, bxy.x);
    float ry = fmaf(s[1], dn, bxy.y);
    ((__half2*)out)[(size_t)nB * 64 + lane] =
        __floats2half2_rn(fmaxf(rx, 0.f), fmaxf(ry, 0.f));
  }
}

// ---------------------------------------------------------------------------
// Pool + graph boundaries (batch sorted)
// ---------------------------------------------------------------------------
__global__ __launch_bounds__(128) void k_pool(
    const __half* __restrict__ h, const int* __restrict__ batch,
    float* __restrict__ gsum, int* __restrict__ gstart,
    int* __restrict__ gend, int N) {
  int ch = threadIdx.x;
  int n0 = blockIdx.x * 128;
  int n1 = n0 + 128; if (n1 > N) n1 = N;
  if (n0 >= N) return;
  for (int n = n0 + ch; n < n1; n += 128) {
    int g = batch[n];
    if (n == 0 || batch[n - 1] != g) gstart[g] = n;
    if (n == N - 1 || batch[n + 1] != g) gend[g] = n + 1;
  }
  float acc = 0.f;
  int curg = batch[n0];
  for (int n = n0; n < n1; ++n) {
    int g = batch[n];
    if (g != curg) {
      atomicAdd(&gsum[curg * CH + ch], acc);
      acc = 0.f; curg = g;
    }
    acc += __half2float(h[(size_t)n * CH + ch]);
  }
  atomicAdd(&gsum[curg * CH + ch], acc);
}

// ---------------------------------------------------------------------------
// FC
// ---------------------------------------------------------------------------
__global__ __launch_bounds__(64) void k_fc(
    const float* __restrict__ gsum, const int* __restrict__ gstart,
    const int* __restrict__ gend, const float* __restrict__ Wfc,
    const float* __restrict__ bfc, float* __restrict__ outp) {
  int g = blockIdx.x;
  int j = threadIdx.x;
  if (j >= NCLS) return;
  int cnt = gend[g] - gstart[g];
  float invc = 1.0f / fmaxf((float)cnt, 1.0f);
  float acc = 0.0f;
  for (int c = 0; c < CH; ++c)
    acc = fmaf(gsum[g * CH + c], Wfc[c * NCLS + j], acc);
  outp[g * NCLS + j] = fmaf(acc, invc, bfc[j]);
}

// ---------------------------------------------------------------------------
extern "C" void kernel_launch(void* const* d_in, const int* in_sizes, int n_in,
                              void* d_out, int out_size, void* d_ws, size_t ws_size,
                              hipStream_t stream) {
  const float* x    = (const float*)d_in[0];
  const int*   ei   = (const int*)d_in[1];
  const int*   batch= (const int*)d_in[2];
  const float* W1   = (const float*)d_in[3];
  const float* b1   = (const float*)d_in[4];
  const float* W2   = (const float*)d_in[5];
  const float* b2   = (const float*)d_in[6];
  const float* Wfc  = (const float*)d_in[7];
  const float* bfc  = (const float*)d_in[8];
  float* outp = (float*)d_out;

  const int N = in_sizes[0] / CH;       // 100000
  const int E = in_sizes[1] / 2;        // 3200000
  const int* src = ei;
  const int* dst = ei + E;
  const int NBUCK = (N + BW - 1) >> BSHIFT;   // 391
  // Over-allocated bucket capacity: mean + ~14 sigma + 4-align padding room.
  int CAP = (E / NBUCK) + (E / NBUCK) / 8 + 1280;
  CAP = (CAP + 3) & ~3;                       // keep per-bucket base 4-aligned

  // Workspace carve (256B aligned). First three buffers zeroed by ONE memset.
  char* w = (char*)d_ws;
  size_t o = 0;
  auto carve = [&](size_t bytes) -> void* {
    o = (o + 255) & ~(size_t)255;
    void* p = w + o;
    o += bytes;
    return p;
  };
  float*    gsum   = (float*)   carve((size_t)NGRAPH * CH * 4);  // zeroed
  int*      gstart = (int*)     carve((size_t)NGRAPH * 4);       // zeroed
  int*      gend   = (int*)     carve((size_t)NGRAPH * 4);       // zeroed
  size_t zbytes = o;
  int*      offs   = (int*)     carve((size_t)N * 4);
  int*      oendb  = (int*)     carve((size_t)N * 4);
  int*      gcur   = (int*)     carve(MAXB * 4);
  int*      csr    = (int*)     carve((size_t)NBUCK * CAP * 4);
  float*    dinv   = (float*)   carve((size_t)N * 4);
  _Float16* WhT1   = (_Float16*)carve((size_t)CH * CH * 2);
  _Float16* WhT2   = (_Float16*)carve((size_t)CH * CH * 2);
  unsigned char* xsbuf = (unsigned char*)carve((size_t)(N + 1) * CH); // fp8 + zero row
  __half*   hbuf   = (__half*)  carve((size_t)N * CH * 2);            // fp16 h
  (void)ws_size;

  // ebuf (packed edges, gapped) aliases hbuf: NBUCK*CAP*4 ~ 16.4MB <= 25.6MB
  int* ebuf = (int*)hbuf;

  (void)hipMemsetAsync(gsum, 0, zbytes, stream);

  const int GB64 = (N + 63) / 64;       // 1563
  const int GB   = (N + 127) / 128;
  const int AB   = (N + 7) / 8;         // 2 nodes/wave, 4 waves/block

  k_init_wt<<<129, 256, 0, stream>>>(gcur, CAP, NBUCK,
                                     (int*)(xsbuf + (size_t)N * CH),
                                     W1, W2, WhT1, WhT2);
  k_scatter<<<(E + 8191) / 8192, 1024, 0, stream>>>(src, dst, gcur, ebuf, E);
  k_build  <<<NBUCK, 1024, 0, stream>>>(ebuf, gcur, offs, oendb, dinv, csr, N, CAP);

  // Layer 1: xs = fp8((x@W1)*dinv*64) ; h = fp16(relu(agg(xs)*dinv/64 + b1))
  k_gemm_f32<<<GB64, 256, 0, stream>>>(x, WhT1, dinv, xsbuf, N);
  k_agg<<<AB, 256, 0, stream>>>(xsbuf, csr, offs, oendb, dinv, b1, hbuf, N);
  // Layer 2
  k_gemm_f16<<<GB64, 256, 0, stream>>>((const _Float16*)hbuf, WhT2, dinv, xsbuf, N);
  k_agg<<<AB, 256, 0, stream>>>(xsbuf, csr, offs, oendb, dinv, b2, hbuf, N);

  // Pool (+ boundaries) + FC
  k_pool<<<GB, 128, 0, stream>>>(hbuf, batch, gsum, gstart, gend, N);
  k_fc<<<NGRAPH, 64, 0, stream>>>(gsum, gstart, gend, Wfc, bfc, outp);
  (void)out_size; (void)n_in;
}

// Round 3
// 350.039 us; speedup vs baseline: 1.2854x; 1.0299x over previous
//
#include <hip/hip_runtime.h>
#include <hip/hip_bf16.h>
#include <hip/hip_fp16.h>

// Problem constants (match reference)
static constexpr int CH     = 128;   // IN_CH == HID
static constexpr int NCLS   = 32;
static constexpr int NGRAPH = 256;

// Bucketed CSR build: buckets are 256-node ranges (bucket = dst >> 8).
static constexpr int BSHIFT = 8;
static constexpr int BW     = 1 << BSHIFT;   // 256 nodes per bucket
static constexpr int MAXB   = 512;

typedef _Float16 half8 __attribute__((ext_vector_type(8)));
typedef _Float16 half4 __attribute__((ext_vector_type(4)));
typedef float    f32x4 __attribute__((ext_vector_type(4)));
typedef float    f32x2 __attribute__((ext_vector_type(2)));

// fp8 (OCP e4m3) gather buffer: xs rows quantized with a static scale so
// layer-2 values (~0.01 raw) stay in e4m3 normal range.
static constexpr float FP8_SCALE = 64.0f;
static constexpr float FP8_INV   = 1.0f / 64.0f;

__device__ __forceinline__ f32x2 dec8(unsigned short u) {
  // two e4m3 bytes (low word) -> two f32 (one VALU op)
  return __builtin_amdgcn_cvt_pk_f32_fp8((int)u, false);
}
__device__ __forceinline__ unsigned char enc8(float v) {
  return (unsigned char)(__builtin_amdgcn_cvt_pk_fp8_f32(v, v, 0, false) & 0xFF);
}

// ---------------------------------------------------------------------------
// 1) init: block 0 sets bucket cursors to b*CAP and zeroes the fp8 pad row
//    (row N of xs; CSR padding points here so padded gathers add +0.0).
//    blocks 1..128: W1,W2 -> fp16 transpose.
// ---------------------------------------------------------------------------
__global__ __launch_bounds__(256) void k_init_wt(
    int* __restrict__ gcur, int CAP, int NBUCK, int* __restrict__ xzero,
    const float* __restrict__ W1, const float* __restrict__ W2,
    _Float16* __restrict__ WhT1, _Float16* __restrict__ WhT2) {
  int t = threadIdx.x;
  if (blockIdx.x == 0) {
    for (int i = t; i < NBUCK; i += 256) gcur[i] = i * CAP;
    if (t < 32) xzero[t] = 0;              // 128B zero row
    return;
  }
  int i = (blockIdx.x - 1) * 256 + t;       // 0..32767
  const float* W = (i < CH * CH) ? W1 : W2;
  _Float16* T   = (i < CH * CH) ? WhT1 : WhT2;
  int j = i & (CH * CH - 1);
  int k = j >> 7, n = j & 127;
  T[n * CH + k] = (_Float16)W[j];
}

// ---------------------------------------------------------------------------
// 2) scatter packed edges into over-allocated bucket regions.
//    pack = (dstlo << 17) | src   (dstlo < 256 -> 8 bits; src < 2^17)
// ---------------------------------------------------------------------------
__global__ __launch_bounds__(1024) void k_scatter(
    const int* __restrict__ src, const int* __restrict__ dst,
    int* __restrict__ gcur, int* __restrict__ ebuf, int E) {
  __shared__ int bcnt[MAXB];
  __shared__ int bbase[MAXB];
  int t = threadIdx.x;
  if (t < MAXB) bcnt[t] = 0;
  __syncthreads();
  int base = blockIdx.x * 8192;
  int s_[8], d_[8], r_[8];
  #pragma unroll
  for (int j = 0; j < 8; ++j) {
    int i = base + j * 1024 + t;
    if (i < E) {
      s_[j] = src[i];
      d_[j] = dst[i];
      r_[j] = atomicAdd(&bcnt[d_[j] >> BSHIFT], 1);
    }
  }
  __syncthreads();
  if (t < MAXB && bcnt[t]) bbase[t] = atomicAdd(&gcur[t], bcnt[t]);
  __syncthreads();
  #pragma unroll
  for (int j = 0; j < 8; ++j) {
    int i = base + j * 1024 + t;
    if (i < E) {
      int b = d_[j] >> BSHIFT;
      int p = ((d_[j] & (BW - 1)) << 17) | s_[j];
      ebuf[bbase[b] + r_[j]] = p;
    }
  }
}

// ---------------------------------------------------------------------------
// 3) per-bucket CSR build (packed edges, gapped CAP regions).
//    Per-node regions are 4-entry aligned; slots [deg, pdeg) are filled with
//    NPAD (= N, the zero row) so k_agg can read blind int4 chunks.
// ---------------------------------------------------------------------------
__global__ __launch_bounds__(1024) void k_build(
    const int* __restrict__ ebuf, const int* __restrict__ gcur,
    int* __restrict__ offs, int* __restrict__ oend,
    float* __restrict__ dinv, int* __restrict__ csr, int N, int CAP) {
  __shared__ int sdeg[BW];
  __shared__ int sscan[BW];
  int b = blockIdx.x;
  int t = threadIdx.x;
  int lo = b << BSHIFT;
  int e0 = b * CAP;
  int e1 = gcur[b];                  // b*CAP + bucket count after scatter

  if (t < BW) sdeg[t] = 0;
  __syncthreads();
  for (int e = e0 + t; e < e1; e += 1024)
    atomicAdd(&sdeg[ebuf[e] >> 17], 1);
  __syncthreads();
  if (t < BW) sscan[t] = (sdeg[t] + 3) & ~3;     // padded degree
  __syncthreads();
  for (int st = 1; st < BW; st <<= 1) {
    int v = (t < BW && t >= st) ? sscan[t - st] : 0;
    __syncthreads();
    if (t < BW) sscan[t] += v;
    __syncthreads();
  }
  if (t < BW) {
    int deg  = sdeg[t];
    int pdeg = (deg + 3) & ~3;
    int ex = b * CAP + sscan[t] - pdeg;          // 4-aligned (CAP%4==0)
    int n = lo + t;
    if (n < N) {
      offs[n] = ex;
      oend[n] = ex + deg;
      dinv[n] = 1.0f / sqrtf((float)(deg + 1));
      for (int q = deg; q < pdeg; ++q) csr[ex + q] = N;   // zero-row pad
    }
    sscan[t] = ex;                                // fill cursor
  }
  __syncthreads();
  for (int e = e0 + t; e < e1; e += 1024) {
    int p = ebuf[e];
    int pos = atomicAdd(&sscan[p >> 17], 1);
    csr[pos] = p & 0x1FFFF;
  }
}

// ---------------------------------------------------------------------------
// MFMA GEMM: 64-row tiles, 4 waves x 16 rows, K=128 single shot, epilogue
// scales by dinv*64 -> fp8 e4m3 (scaled-xs form).
// ---------------------------------------------------------------------------
__device__ __forceinline__ void stage_w(const _Float16* __restrict__ WhT,
                                        _Float16 (*Ws)[136], int tid) {
  #pragma unroll
  for (int l = 0; l < 8; ++l) {
    int idx = tid + l * 256;            // 0..2047 half8 chunks
    int n = idx >> 4, k8 = (idx & 15) << 3;
    *(half8*)&Ws[n][k8] = *(const half8*)(WhT + n * CH + k8);
  }
}

__device__ __forceinline__ void gemm_core64(
    const _Float16 (*As)[136], const _Float16 (*Ws)[136],
    const float* __restrict__ dinv, unsigned char* __restrict__ C,
    int row0, int M, int tid) {
  int lane = tid & 63, wave = tid >> 6;
  int quad = lane >> 4, sub = lane & 15;
  int m0 = wave * 16;

  f32x4 acc[8];
  #pragma unroll
  for (int j = 0; j < 8; ++j) acc[j] = (f32x4){0.f, 0.f, 0.f, 0.f};

  #pragma unroll
  for (int kc = 0; kc < 4; ++kc) {
    int ko = kc * 32 + quad * 8;
    half8 a = *(const half8*)&As[m0 + sub][ko];
    #pragma unroll
    for (int nt = 0; nt < 8; ++nt) {
      half8 b = *(const half8*)&Ws[nt * 16 + sub][ko];
      acc[nt] = __builtin_amdgcn_mfma_f32_16x16x32_f16(a, b, acc[nt], 0, 0, 0);
    }
  }
  #pragma unroll
  for (int r = 0; r < 4; ++r) {
    int row = row0 + m0 + quad * 4 + r;
    if (row < M) {
      float d = dinv[row] * FP8_SCALE;
      #pragma unroll
      for (int nt = 0; nt < 8; ++nt)
        C[(size_t)row * CH + nt * 16 + sub] = enc8(acc[nt][r] * d);
    }
  }
}

// A input fp32 (layer 1: x), packed half4 LDS stores
__global__ __launch_bounds__(256) void k_gemm_f32(
    const float* __restrict__ A, const _Float16* __restrict__ WhT,
    const float* __restrict__ dinv, unsigned char* __restrict__ C, int M) {
  __shared__ _Float16 As[64][136];
  __shared__ _Float16 Ws[128][136];
  int tid = threadIdx.x;
  int row0 = blockIdx.x * 64;
  #pragma unroll
  for (int l = 0; l < 8; ++l) {
    int idx = tid + l * 256;
    int r = idx >> 5, c4 = (idx & 31) << 2;
    int rr = row0 + r; if (rr >= M) rr = M - 1;
    float4 v = *(const float4*)(A + (size_t)rr * CH + c4);
    half4 hv = { (_Float16)v.x, (_Float16)v.y, (_Float16)v.z, (_Float16)v.w };
    *(half4*)&As[r][c4] = hv;
  }
  stage_w(WhT, Ws, tid);
  __syncthreads();
  gemm_core64(As, Ws, dinv, C, row0, M, tid);
}

// A input fp16 (layer 2: h)
__global__ __launch_bounds__(256) void k_gemm_f16(
    const _Float16* __restrict__ A, const _Float16* __restrict__ WhT,
    const float* __restrict__ dinv, unsigned char* __restrict__ C, int M) {
  __shared__ _Float16 As[64][136];
  __shared__ _Float16 Ws[128][136];
  int tid = threadIdx.x;
  int row0 = blockIdx.x * 64;
  #pragma unroll
  for (int l = 0; l < 4; ++l) {
    int idx = tid + l * 256;
    int r = idx >> 4, c8 = (idx & 15) << 3;
    int rr = row0 + r; if (rr >= M) rr = M - 1;
    *(half8*)&As[r][c8] = *(const half8*)(A + (size_t)rr * CH + c8);
  }
  stage_w(WhT, Ws, tid);
  __syncthreads();
  gemm_core64(As, Ws, dinv, C, row0, M, tid);
}

// ---------------------------------------------------------------------------
// Aggregation (pull, CSR): xs pre-scaled fp8 e4m3 (x64), rows 128B.
// MLP-restore version: 2-chunk unroll per node (16 gathers = 32 sectors in
// flight, matching R0's depth at half the bytes), CSR prefetch for the next
// iteration issued UNDER the gather latency, grid-stride waves (no block
// churn). Prefetch-past-end is bounded inside the over-allocated csr region.
// ---------------------------------------------------------------------------
__global__ __launch_bounds__(256) void k_agg(
    const unsigned char* __restrict__ xs, const int* __restrict__ csr,
    const int* __restrict__ offs, const int* __restrict__ oend,
    const float* __restrict__ dinv, const float* __restrict__ bias,
    __half* __restrict__ out, int N) {
  int wid0  = blockIdx.x * 4 + (threadIdx.x >> 6);
  int lane  = threadIdx.x & 63;
  int wstep = gridDim.x * 4;
  unsigned int lane2 = (unsigned int)lane << 1;
  float2 bxy = *(const float2*)(bias + 2 * lane);

  auto g = [&](int s) -> unsigned short {
    return *(const unsigned short*)(xs + (((unsigned int)s << 7) | lane2));
  };

  for (int wid = wid0; wid * 2 < N; wid += wstep) {
    int nA = wid * 2, nB = nA + 1;
    bool hasB = (nB < N);

    int eA = offs[nA];
    int cA = (oend[nA] - eA + 3) >> 2;                 // chunk count
    int eB = hasB ? offs[nB] : eA;
    int cB = hasB ? ((oend[nB] - eB + 3) >> 2) : 0;

    f32x2 aA0 = dec8(g(nA));
    f32x2 aA1 = {0.f, 0.f};
    f32x2 aB0 = {0.f, 0.f}, aB1 = {0.f, 0.f};
    if (hasB) aB0 = dec8(g(nB));

    // ---- lockstep main: 16 gathers in flight, csr prefetched one iter ahead
    if (cA >= 2 && cB >= 2) {
      int4 ca0 = *(const int4*)(csr + eA);
      int4 ca1 = *(const int4*)(csr + eA + 4);
      int4 cb0 = *(const int4*)(csr + eB);
      int4 cb1 = *(const int4*)(csr + eB + 4);
      do {
        unsigned short uA0 = g(ca0.x), uA1 = g(ca0.y), uA2 = g(ca0.z), uA3 = g(ca0.w);
        unsigned short uA4 = g(ca1.x), uA5 = g(ca1.y), uA6 = g(ca1.z), uA7 = g(ca1.w);
        unsigned short uB0 = g(cb0.x), uB1 = g(cb0.y), uB2 = g(cb0.z), uB3 = g(cb0.w);
        unsigned short uB4 = g(cb1.x), uB5 = g(cb1.y), uB6 = g(cb1.z), uB7 = g(cb1.w);
        eA += 8; eB += 8; cA -= 2; cB -= 2;
        // prefetch next chunks (unconditional; bounded by csr over-allocation)
        int4 na0 = *(const int4*)(csr + eA);
        int4 na1 = *(const int4*)(csr + eA + 4);
        int4 nb0 = *(const int4*)(csr + eB);
        int4 nb1 = *(const int4*)(csr + eB + 4);
        aA0 += dec8(uA0); aA1 += dec8(uA1); aA0 += dec8(uA2); aA1 += dec8(uA3);
        aA0 += dec8(uA4); aA1 += dec8(uA5); aA0 += dec8(uA6); aA1 += dec8(uA7);
        aB0 += dec8(uB0); aB1 += dec8(uB1); aB0 += dec8(uB2); aB1 += dec8(uB3);
        aB0 += dec8(uB4); aB1 += dec8(uB5); aB0 += dec8(uB6); aB1 += dec8(uB7);
        ca0 = na0; ca1 = na1; cb0 = nb0; cb1 = nb1;
      } while (cA >= 2 && cB >= 2);
    }

    // ---- per-node drain: 2-chunk (8 gathers) then 1-chunk (4 gathers)
    auto drain = [&](int e, int c, f32x2& a0, f32x2& a1) {
      while (c >= 2) {
        int4 q0 = *(const int4*)(csr + e);
        int4 q1 = *(const int4*)(csr + e + 4);
        unsigned short u0 = g(q0.x), u1 = g(q0.y), u2 = g(q0.z), u3 = g(q0.w);
        unsigned short u4 = g(q1.x), u5 = g(q1.y), u6 = g(q1.z), u7 = g(q1.w);
        a0 += dec8(u0); a1 += dec8(u1); a0 += dec8(u2); a1 += dec8(u3);
        a0 += dec8(u4); a1 += dec8(u5); a0 += dec8(u6); a1 += dec8(u7);
        e += 8; c -= 2;
      }
      if (c > 0) {
        int4 q0 = *(const int4*)(csr + e);
        unsigned short u0 = g(q0.x), u1 = g(q0.y), u2 = g(q0.z), u3 = g(q0.w);
        a0 += dec8(u0); a1 += dec8(u1); a0 += dec8(u2); a1 += dec8(u3);
      }
    };
    drain(eA, cA, aA0, aA1);
    if (hasB) drain(eB, cB, aB0, aB1);

    {
      f32x2 s = aA0 + aA1;
      float dn = dinv[nA] * FP8_INV;
      float rx = fmaf(s[0], dn, bxy.x);
      float ry = fmaf(s[1], dn, bxy.y);
      ((__half2*)out)[(size_t)nA * 64 + lane] =
          __floats2half2_rn(fmaxf(rx, 0.f), fmaxf(ry, 0.f));
    }
    if (hasB) {
      f32x2 s = aB0 + aB1;
      float dn = dinv[nB] * FP8_INV;
      float rx = fmaf(s[0], dn, bxy.x);
      float ry = fmaf(s[1], dn, bxy.y);
      ((__half2*)out)[(size_t)nB * 64 + lane] =
          __floats2half2_rn(fmaxf(rx, 0.f), fmaxf(ry, 0.f));
    }
  }
}

// ---------------------------------------------------------------------------
// Pool + graph boundaries (batch sorted)
// ---------------------------------------------------------------------------
__global__ __launch_bounds__(128) void k_pool(
    const __half* __restrict__ h, const int* __restrict__ batch,
    float* __restrict__ gsum, int* __restrict__ gstart,
    int* __restrict__ gend, int N) {
  int ch = threadIdx.x;
  int n0 = blockIdx.x * 128;
  int n1 = n0 + 128; if (n1 > N) n1 = N;
  if (n0 >= N) return;
  for (int n = n0 + ch; n < n1; n += 128) {
    int g = batch[n];
    if (n == 0 || batch[n - 1] != g) gstart[g] = n;
    if (n == N - 1 || batch[n + 1] != g) gend[g] = n + 1;
  }
  float acc = 0.f;
  int curg = batch[n0];
  for (int n = n0; n < n1; ++n) {
    int g = batch[n];
    if (g != curg) {
      atomicAdd(&gsum[curg * CH + ch], acc);
      acc = 0.f; curg = g;
    }
    acc += __half2float(h[(size_t)n * CH + ch]);
  }
  atomicAdd(&gsum[curg * CH + ch], acc);
}

// ---------------------------------------------------------------------------
// FC
// ---------------------------------------------------------------------------
__global__ __launch_bounds__(64) void k_fc(
    const float* __restrict__ gsum, const int* __restrict__ gstart,
    const int* __restrict__ gend, const float* __restrict__ Wfc,
    const float* __restrict__ bfc, float* __restrict__ outp) {
  int g = blockIdx.x;
  int j = threadIdx.x;
  if (j >= NCLS) return;
  int cnt = gend[g] - gstart[g];
  float invc = 1.0f / fmaxf((float)cnt, 1.0f);
  float acc = 0.0f;
  for (int c = 0; c < CH; ++c)
    acc = fmaf(gsum[g * CH + c], Wfc[c * NCLS + j], acc);
  outp[g * NCLS + j] = fmaf(acc, invc, bfc[j]);
}

// ---------------------------------------------------------------------------
extern "C" void kernel_launch(void* const* d_in, const int* in_sizes, int n_in,
                              void* d_out, int out_size, void* d_ws, size_t ws_size,
                              hipStream_t stream) {
  const float* x    = (const float*)d_in[0];
  const int*   ei   = (const int*)d_in[1];
  const int*   batch= (const int*)d_in[2];
  const float* W1   = (const float*)d_in[3];
  const float* b1   = (const float*)d_in[4];
  const float* W2   = (const float*)d_in[5];
  const float* b2   = (const float*)d_in[6];
  const float* Wfc  = (const float*)d_in[7];
  const float* bfc  = (const float*)d_in[8];
  float* outp = (float*)d_out;

  const int N = in_sizes[0] / CH;       // 100000
  const int E = in_sizes[1] / 2;        // 3200000
  const int* src = ei;
  const int* dst = ei + E;
  const int NBUCK = (N + BW - 1) >> BSHIFT;   // 391
  // Over-allocated bucket capacity: mean + ~14 sigma + 4-align padding room.
  int CAP = (E / NBUCK) + (E / NBUCK) / 8 + 1280;
  CAP = (CAP + 3) & ~3;                       // keep per-bucket base 4-aligned

  // Workspace carve (256B aligned). First three buffers zeroed by ONE memset.
  char* w = (char*)d_ws;
  size_t o = 0;
  auto carve = [&](size_t bytes) -> void* {
    o = (o + 255) & ~(size_t)255;
    void* p = w + o;
    o += bytes;
    return p;
  };
  float*    gsum   = (float*)   carve((size_t)NGRAPH * CH * 4);  // zeroed
  int*      gstart = (int*)     carve((size_t)NGRAPH * 4);       // zeroed
  int*      gend   = (int*)     carve((size_t)NGRAPH * 4);       // zeroed
  size_t zbytes = o;
  int*      offs   = (int*)     carve((size_t)N * 4);
  int*      oendb  = (int*)     carve((size_t)N * 4);
  int*      gcur   = (int*)     carve(MAXB * 4);
  int*      csr    = (int*)     carve((size_t)NBUCK * CAP * 4);
  float*    dinv   = (float*)   carve((size_t)N * 4);
  _Float16* WhT1   = (_Float16*)carve((size_t)CH * CH * 2);
  _Float16* WhT2   = (_Float16*)carve((size_t)CH * CH * 2);
  unsigned char* xsbuf = (unsigned char*)carve((size_t)(N + 1) * CH); // fp8 + zero row
  __half*   hbuf   = (__half*)  carve((size_t)N * CH * 2);            // fp16 h
  (void)ws_size;

  // ebuf (packed edges, gapped) aliases hbuf: NBUCK*CAP*4 ~ 16.4MB <= 25.6MB
  int* ebuf = (int*)hbuf;

  (void)hipMemsetAsync(gsum, 0, zbytes, stream);

  const int GB64 = (N + 63) / 64;       // 1563
  const int GB   = (N + 127) / 128;
  // k_agg: grid-stride, 2 nodes/wave, 4 waves/block; 2048 blocks ~ 8192 waves
  int AB = (N + 7) / 8;
  if (AB > 2048) AB = 2048;

  k_init_wt<<<129, 256, 0, stream>>>(gcur, CAP, NBUCK,
                                     (int*)(xsbuf + (size_t)N * CH),
                                     W1, W2, WhT1, WhT2);
  k_scatter<<<(E + 8191) / 8192, 1024, 0, stream>>>(src, dst, gcur, ebuf, E);
  k_build  <<<NBUCK, 1024, 0, stream>>>(ebuf, gcur, offs, oendb, dinv, csr, N, CAP);

  // Layer 1: xs = fp8((x@W1)*dinv*64) ; h = fp16(relu(agg(xs)*dinv/64 + b1))
  k_gemm_f32<<<GB64, 256, 0, stream>>>(x, WhT1, dinv, xsbuf, N);
  k_agg<<<AB, 256, 0, stream>>>(xsbuf, csr, offs, oendb, dinv, b1, hbuf, N);
  // Layer 2
  k_gemm_f16<<<GB64, 256, 0, stream>>>((const _Float16*)hbuf, WhT2, dinv, xsbuf, N);
  k_agg<<<AB, 256, 0, stream>>>(xsbuf, csr, offs, oendb, dinv, b2, hbuf, N);

  // Pool (+ boundaries) + FC
  k_pool<<<GB, 128, 0, stream>>>(hbuf, batch, gsum, gstart, gend, N);
  k_fc<<<NGRAPH, 64, 0, stream>>>(gsum, gstart, gend, Wfc, bfc, outp);
  (void)out_size; (void)n_in;
}